// Round 6
// baseline (82.928 us; speedup 1.0000x reference)
//
#include <hip/hip_runtime.h>

// Sizes (fixed):
// pc1_0: [8,2048,3] -> 16384 pts   d_in[0]
// pc1_1: [8, 512,3] ->  4096 pts   d_in[1]
// pc1_3: [8, 256,1] ->  2048 vals  d_in[2]
// pc2  : [8,2048,3] -> 16384 pts   d_in[3]
// pc3  : [8, 256,3] ->  2048 pts   d_in[4]
//
// ws layout (floats):
//   [0      ,16384) minA0 : pc1_0 -> pc2   (cd, a->b)
//   [16384  ,32768) minB0 : pc2   -> pc1_0 (cd, b->a)
//   [32768  ,36864) minA1 : pc1_1 -> pc2   (seed, a->b)
//   [36864  ,53248) minB1 : pc2   -> pc1_1 (seed, b->a)
//   [53248  ,55296) minC  : pc3[b] -> pc2[b] (confidence)
//   [55296  ,55304) acc[8]
//   [55304]         ticket

#define N_MINS 55296
#define R 16  // A-points per thread

typedef float v2f __attribute__((ext_vector_type(2)));

__device__ __forceinline__ float blockReduceSum(float v, float* sbuf) {
#pragma unroll
  for (int off = 32; off > 0; off >>= 1) v += __shfl_down(v, off, 64);
  int lane = threadIdx.x & 63;
  int wid  = threadIdx.x >> 6;
  if (lane == 0) sbuf[wid] = v;
  __syncthreads();
  float r = 0.f;
  if (threadIdx.x == 0) r = sbuf[0] + sbuf[1] + sbuf[2] + sbuf[3];
  return r;
}

// Fused NN-min kernel. d2 = |a|^2 + (|b|^2 - 2 a.b); |a|^2 folded in after
// the min. Inner loop: 2 B-points per step via explicit v_pk_fma_f32 +
// v_min3_f32 => 4 instr per 2 pairs per A-point.
// LDS tile (64 pair-entries for a 128-point B tile):
//   tile[p]    = (-2x0,-2x1,-2y0,-2y1)
//   tile[64+p] = (-2z0,-2z1, w0,  w1)   w = |b|^2
__global__ __launch_bounds__(256) void k_nn_all(
    const float* __restrict__ pc10, const float* __restrict__ pc11,
    const float* __restrict__ pc2, const float* __restrict__ pc3,
    float* __restrict__ ws) {
  const int tid = threadIdx.x;
  const int blk = blockIdx.x;
  __shared__ float4 tile[256];

  if (blk >= 1280) {  // confidence job: per-batch NN pc3[b] -> pc2[b]
    int j = blk - 1280;
    int b = j >> 3;
    int s = j & 7;
    int bi = b * 2048 + s * 256 + tid;
    {
      float bx = pc2[bi * 3 + 0], by = pc2[bi * 3 + 1], bz = pc2[bi * 3 + 2];
      tile[tid] = make_float4(-2.f * bx, -2.f * by, -2.f * bz,
                              bx * bx + by * by + bz * bz);
    }
    int i = b * 256 + tid;
    float ax = pc3[i * 3 + 0], ay = pc3[i * 3 + 1], az = pc3[i * 3 + 2];
    float ra = ax * ax + ay * ay + az * az;
    __syncthreads();
    float mn = 3.0e38f;
#pragma unroll 4
    for (int t = 0; t < 256; ++t) {
      float4 q = tile[t];
      float v = fmaf(q.x, ax, fmaf(q.y, ay, fmaf(q.z, az, q.w)));
      mn = fminf(mn, v);
    }
    atomicMin((unsigned int*)(ws + 53248 + i), __float_as_uint(fmaxf(mn + ra, 0.f)));
    return;
  }

  const float* A;
  const float* B;
  float* outMin;
  int aBase, bBase;
  if (blk < 512) {            // job1: pc1_0 (16384) -> pc2 (16384)
    A = pc10; B = pc2; outMin = ws + 0;
    aBase = (blk >> 7) * 4096; bBase = (blk & 127) * 128;
  } else if (blk < 1024) {    // job2: pc2 (16384) -> pc1_0 (16384)
    int j = blk - 512;
    A = pc2; B = pc10; outMin = ws + 16384;
    aBase = (j >> 7) * 4096; bBase = (j & 127) * 128;
  } else if (blk < 1152) {    // job3: pc1_1 (4096) -> pc2 (16384)
    int j = blk - 1024;
    A = pc11; B = pc2; outMin = ws + 32768;
    aBase = 0; bBase = j * 128;
  } else {                    // job4: pc2 (16384) -> pc1_1 (4096)
    int j = blk - 1152;
    A = pc2; B = pc11; outMin = ws + 36864;
    aBase = (j >> 5) * 4096; bBase = (j & 31) * 128;
  }

  // stage 128-point B tile in paired-SoA form (64 xy entries + 64 zw entries)
  if (tid < 64) {
    int bi0 = (bBase + 2 * tid) * 3;
    float x0 = B[bi0 + 0], y0 = B[bi0 + 1];
    float x1 = B[bi0 + 3], y1 = B[bi0 + 4];
    tile[tid] = make_float4(-2.f * x0, -2.f * x1, -2.f * y0, -2.f * y1);
  } else if (tid < 128) {
    int p = tid - 64;
    int bi0 = (bBase + 2 * p) * 3;
    float x0 = B[bi0 + 0], y0 = B[bi0 + 1], z0 = B[bi0 + 2];
    float x1 = B[bi0 + 3], y1 = B[bi0 + 4], z1 = B[bi0 + 5];
    tile[64 + p] = make_float4(-2.f * z0, -2.f * z1,
                               x0 * x0 + y0 * y0 + z0 * z0,
                               x1 * x1 + y1 * y1 + z1 * z1);
  }

  v2f axx[R], ayy[R], azz[R];
  float mn[R];
#pragma unroll
  for (int r = 0; r < R; ++r) {
    int ai = aBase + r * 256 + tid;
    float ax = A[ai * 3 + 0];
    float ay = A[ai * 3 + 1];
    float az = A[ai * 3 + 2];
    axx[r] = (v2f){ax, ax};
    ayy[r] = (v2f){ay, ay};
    azz[r] = (v2f){az, az};
    mn[r] = 3.0e38f;
  }
  __syncthreads();

#pragma unroll 2
  for (int p = 0; p < 64; ++p) {
    float4 qxy = tile[p];
    float4 qzw = tile[64 + p];
    v2f qx = (v2f){qxy.x, qxy.y};
    v2f qy = (v2f){qxy.z, qxy.w};
    v2f qz = (v2f){qzw.x, qzw.y};
    v2f qw = (v2f){qzw.z, qzw.w};
#pragma unroll
    for (int r = 0; r < R; ++r) {
      v2f acc_;
      asm("v_pk_fma_f32 %0, %1, %2, %3"
          : "=v"(acc_) : "v"(qz), "v"(azz[r]), "v"(qw));
      asm("v_pk_fma_f32 %0, %1, %2, %0"
          : "+v"(acc_) : "v"(qy), "v"(ayy[r]));
      asm("v_pk_fma_f32 %0, %1, %2, %0"
          : "+v"(acc_) : "v"(qx), "v"(axx[r]));
      asm("v_min3_f32 %0, %0, %1, %2"
          : "+v"(mn[r]) : "v"(acc_.x), "v"(acc_.y));
    }
  }

#pragma unroll
  for (int r = 0; r < R; ++r) {
    int ai = aBase + r * 256 + tid;
    float ax = axx[r].x, ay = ayy[r].x, az = azz[r].x;
    float ra = fmaf(ax, ax, fmaf(ay, ay, az * az));
    atomicMin((unsigned int*)(outMin + ai),
              __float_as_uint(fmaxf(mn[r] + ra, 0.f)));
  }
}

// Segmented reduce + final combine (ticket: last block writes out).
__global__ __launch_bounds__(256) void k_reduce(
    const float* __restrict__ ws, const float* __restrict__ pc13,
    const float* __restrict__ pc10, const float* __restrict__ pc2,
    float* __restrict__ acc, unsigned int* __restrict__ ticket,
    float* __restrict__ out) {
  __shared__ float sbuf[4];
  int idx = blockIdx.x * 256 + threadIdx.x;
  float v;
  int k;
  if (idx < 53248) {
    v = sqrtf(fmaxf(ws[idx], 0.f));
    k = (idx < 16384) ? 0 : (idx < 32768) ? 1 : (idx < 36864) ? 2 : 3;
  } else if (idx < 55296) {
    int i = idx - 53248;
    float score = expf(-sqrtf(fmaxf(ws[idx], 0.f)));
    float d = pc13[i] - score;
    v = d * d;
    k = 4;
  } else {
    int i = idx - 55296;
    float d = pc10[i] - pc2[i];
    v = d * d;
    k = 5;
  }
  float s = blockReduceSum(v, sbuf);
  if (threadIdx.x == 0) {
    atomicAdd(acc + k, s);
    __threadfence();
    unsigned int t = atomicAdd(ticket, 1u);
    if (t == gridDim.x - 1) {
      __threadfence();
      float cd   = (acc[0] + acc[1]) * (1.f / 16384.f);
      float seed = acc[2] * (1.f / 4096.f) + acc[3] * (1.f / 16384.f);
      float conf = acc[4] * (1.f / 2048.f);
      float p2p  = acc[5] * (1.f / 49152.f);
      out[0] = 0.5f * cd + 0.5f * seed + 0.5f * conf + p2p;
    }
  }
}

extern "C" void kernel_launch(void* const* d_in, const int* in_sizes, int n_in,
                              void* d_out, int out_size, void* d_ws, size_t ws_size,
                              hipStream_t stream) {
  const float* pc10 = (const float*)d_in[0];
  const float* pc11 = (const float*)d_in[1];
  const float* pc13 = (const float*)d_in[2];
  const float* pc2  = (const float*)d_in[3];
  const float* pc3  = (const float*)d_in[4];
  float* ws  = (float*)d_ws;
  float* acc = ws + N_MINS;
  float* out = (float*)d_out;

  // init: min arrays to ~3.39e38 (0x7F7F7F7F); acc[8]+ticket to 0
  hipMemsetAsync(ws, 0x7F, N_MINS * sizeof(float), stream);
  hipMemsetAsync(acc, 0, 9 * sizeof(float), stream);

  k_nn_all<<<1344, 256, 0, stream>>>(pc10, pc11, pc2, pc3, ws);

  int reduce_blocks = (N_MINS + 49152) / 256;  // 408
  k_reduce<<<reduce_blocks, 256, 0, stream>>>(ws, pc13, pc10, pc2, acc,
                                              (unsigned int*)(ws + 55304), out);
}

// Round 8
// 80.130 us; speedup vs baseline: 1.0349x; 1.0349x over previous
//
#include <hip/hip_runtime.h>

// Sizes (fixed):
// pc1_0: [8,2048,3] -> 16384 pts   d_in[0]
// pc1_1: [8, 512,3] ->  4096 pts   d_in[1]
// pc1_3: [8, 256,1] ->  2048 vals  d_in[2]
// pc2  : [8,2048,3] -> 16384 pts   d_in[3]
// pc3  : [8, 256,3] ->  2048 pts   d_in[4]
//
// ws layout (floats):
//   [0      ,16384) minA0 : pc1_0 -> pc2   (cd, a->b)
//   [16384  ,32768) minB0 : pc2   -> pc1_0 (cd, b->a)
//   [32768  ,36864) minA1 : pc1_1 -> pc2   (seed, a->b)
//   [36864  ,53248) minB1 : pc2   -> pc1_1 (seed, b->a)
//   [53248  ,55296) minC  : pc3[b] -> pc2[b] (confidence, full f32)
//   [55296  ,55304) acc[8]
//   [55304]         ticket

#define N_MINS 55296
#define R 8  // A-points per thread

typedef _Float16 h2 __attribute__((ext_vector_type(2)));

__device__ __forceinline__ float h2_to_f(h2 v, int i) {
  return (float)v[i];
}
__device__ __forceinline__ float bc_f(h2 v) {
  return __builtin_bit_cast(float, v);
}
__device__ __forceinline__ h2 bc_h2(float f) {
  return __builtin_bit_cast(h2, f);
}

__device__ __forceinline__ float blockReduceSum(float v, float* sbuf) {
#pragma unroll
  for (int off = 32; off > 0; off >>= 1) v += __shfl_down(v, off, 64);
  int lane = threadIdx.x & 63;
  int wid  = threadIdx.x >> 6;
  if (lane == 0) sbuf[wid] = v;
  __syncthreads();
  float r = 0.f;
  if (threadIdx.x == 0) r = sbuf[0] + sbuf[1] + sbuf[2] + sbuf[3];
  return r;
}

// Fused NN-min kernel, fp16-packed inner loop.
// d2 = ra + (w - 2 a.b); chain computed in fp16 pairs (2 B-points/step):
//   3 v_pk_fma_f16 + 1 v_pk_min_f16 per A-point per step = 2 VALU/pair.
// ra (|a|^2) kept f32, folded in after the min. Confidence job stays f32.
// LDS: tile4[p] = 16B = {(-2x0,-2x1),(-2y0,-2y1),(-2z0,-2z1),(w0,w1)} as half2s.
__global__ __launch_bounds__(256) void k_nn_all(
    const float* __restrict__ pc10, const float* __restrict__ pc11,
    const float* __restrict__ pc2, const float* __restrict__ pc3,
    float* __restrict__ ws) {
  const int tid = threadIdx.x;
  const int blk = blockIdx.x;
  __shared__ float4 tile4[256];

  if (blk >= 1280) {  // confidence job: per-batch NN pc3[b] -> pc2[b], f32
    int j = blk - 1280;
    int b = j >> 3;
    int s = j & 7;
    int bi = b * 2048 + s * 256 + tid;
    {
      float bx = pc2[bi * 3 + 0], by = pc2[bi * 3 + 1], bz = pc2[bi * 3 + 2];
      tile4[tid] = make_float4(-2.f * bx, -2.f * by, -2.f * bz,
                               bx * bx + by * by + bz * bz);
    }
    int i = b * 256 + tid;
    float ax = pc3[i * 3 + 0], ay = pc3[i * 3 + 1], az = pc3[i * 3 + 2];
    float ra = ax * ax + ay * ay + az * az;
    __syncthreads();
    float mn = 3.0e38f;
#pragma unroll 4
    for (int t = 0; t < 256; ++t) {
      float4 q = tile4[t];
      float v = fmaf(q.x, ax, fmaf(q.y, ay, fmaf(q.z, az, q.w)));
      mn = fminf(mn, v);
    }
    atomicMin((unsigned int*)(ws + 53248 + i), __float_as_uint(fmaxf(mn + ra, 0.f)));
    return;
  }

  const float* A;
  const float* B;
  float* outMin;
  int aBase, bBase;
  if (blk < 512) {            // job1: pc1_0 (16384) -> pc2 (16384)
    A = pc10; B = pc2; outMin = ws + 0;
    aBase = (blk >> 6) * 2048; bBase = (blk & 63) * 256;
  } else if (blk < 1024) {    // job2: pc2 (16384) -> pc1_0 (16384)
    int j = blk - 512;
    A = pc2; B = pc10; outMin = ws + 16384;
    aBase = (j >> 6) * 2048; bBase = (j & 63) * 256;
  } else if (blk < 1152) {    // job3: pc1_1 (4096) -> pc2 (16384)
    int j = blk - 1024;
    A = pc11; B = pc2; outMin = ws + 32768;
    aBase = (j >> 6) * 2048; bBase = (j & 63) * 256;
  } else {                    // job4: pc2 (16384) -> pc1_1 (4096)
    int j = blk - 1152;
    A = pc2; B = pc11; outMin = ws + 36864;
    aBase = (j >> 4) * 2048; bBase = (j & 15) * 256;
  }

  // stage 256-point B slice as 128 fp16 pair-entries
  if (tid < 128) {
    int bi0 = (bBase + 2 * tid) * 3;
    float x0 = B[bi0 + 0], y0 = B[bi0 + 1], z0 = B[bi0 + 2];
    float x1 = B[bi0 + 3], y1 = B[bi0 + 4], z1 = B[bi0 + 5];
    float4 e;
    e.x = bc_f((h2){(_Float16)(-2.f * x0), (_Float16)(-2.f * x1)});
    e.y = bc_f((h2){(_Float16)(-2.f * y0), (_Float16)(-2.f * y1)});
    e.z = bc_f((h2){(_Float16)(-2.f * z0), (_Float16)(-2.f * z1)});
    e.w = bc_f((h2){(_Float16)(x0 * x0 + y0 * y0 + z0 * z0),
                    (_Float16)(x1 * x1 + y1 * y1 + z1 * z1)});
    tile4[tid] = e;
  }

  h2 axx[R], ayy[R], azz[R], mn2[R];
  float ra[R];
#pragma unroll
  for (int r = 0; r < R; ++r) {
    int ai = aBase + r * 256 + tid;
    float ax = A[ai * 3 + 0];
    float ay = A[ai * 3 + 1];
    float az = A[ai * 3 + 2];
    _Float16 hx = (_Float16)ax, hy = (_Float16)ay, hz = (_Float16)az;
    axx[r] = (h2){hx, hx};
    ayy[r] = (h2){hy, hy};
    azz[r] = (h2){hz, hz};
    ra[r] = fmaf(ax, ax, fmaf(ay, ay, az * az));
    mn2[r] = (h2){(_Float16)65504.f, (_Float16)65504.f};
  }
  __syncthreads();

#pragma unroll 2
  for (int p = 0; p < 128; ++p) {
    float4 q = tile4[p];
    h2 qx = bc_h2(q.x);
    h2 qy = bc_h2(q.y);
    h2 qz = bc_h2(q.z);
    h2 qw = bc_h2(q.w);
#pragma unroll
    for (int r = 0; r < R; ++r) {
      h2 v = __builtin_elementwise_fma(
          qx, axx[r],
          __builtin_elementwise_fma(qy, ayy[r],
                                    __builtin_elementwise_fma(qz, azz[r], qw)));
      mn2[r] = __builtin_elementwise_min(mn2[r], v);
    }
  }

#pragma unroll
  for (int r = 0; r < R; ++r) {
    int ai = aBase + r * 256 + tid;
    float mnf = fminf(h2_to_f(mn2[r], 0), h2_to_f(mn2[r], 1));
    atomicMin((unsigned int*)(outMin + ai),
              __float_as_uint(fmaxf(mnf + ra[r], 0.f)));
  }
}

// Segmented reduce + final combine (ticket: last block writes out).
__global__ __launch_bounds__(256) void k_reduce(
    const float* __restrict__ ws, const float* __restrict__ pc13,
    const float* __restrict__ pc10, const float* __restrict__ pc2,
    float* __restrict__ acc, unsigned int* __restrict__ ticket,
    float* __restrict__ out) {
  __shared__ float sbuf[4];
  int idx = blockIdx.x * 256 + threadIdx.x;
  float v;
  int k;
  if (idx < 53248) {
    v = sqrtf(fmaxf(ws[idx], 0.f));
    k = (idx < 16384) ? 0 : (idx < 32768) ? 1 : (idx < 36864) ? 2 : 3;
  } else if (idx < 55296) {
    int i = idx - 53248;
    float score = expf(-sqrtf(fmaxf(ws[idx], 0.f)));
    float d = pc13[i] - score;
    v = d * d;
    k = 4;
  } else {
    int i = idx - 55296;
    float d = pc10[i] - pc2[i];
    v = d * d;
    k = 5;
  }
  float s = blockReduceSum(v, sbuf);
  if (threadIdx.x == 0) {
    atomicAdd(acc + k, s);
    __threadfence();
    unsigned int t = atomicAdd(ticket, 1u);
    if (t == gridDim.x - 1) {
      __threadfence();
      float cd   = (acc[0] + acc[1]) * (1.f / 16384.f);
      float seed = acc[2] * (1.f / 4096.f) + acc[3] * (1.f / 16384.f);
      float conf = acc[4] * (1.f / 2048.f);
      float p2p  = acc[5] * (1.f / 49152.f);
      out[0] = 0.5f * cd + 0.5f * seed + 0.5f * conf + p2p;
    }
  }
}

extern "C" void kernel_launch(void* const* d_in, const int* in_sizes, int n_in,
                              void* d_out, int out_size, void* d_ws, size_t ws_size,
                              hipStream_t stream) {
  const float* pc10 = (const float*)d_in[0];
  const float* pc11 = (const float*)d_in[1];
  const float* pc13 = (const float*)d_in[2];
  const float* pc2  = (const float*)d_in[3];
  const float* pc3  = (const float*)d_in[4];
  float* ws  = (float*)d_ws;
  float* acc = ws + N_MINS;
  float* out = (float*)d_out;

  // init: min arrays to ~3.39e38 (0x7F7F7F7F); acc[8]+ticket to 0
  hipMemsetAsync(ws, 0x7F, N_MINS * sizeof(float), stream);
  hipMemsetAsync(acc, 0, 9 * sizeof(float), stream);

  k_nn_all<<<1344, 256, 0, stream>>>(pc10, pc11, pc2, pc3, ws);

  int reduce_blocks = (N_MINS + 49152) / 256;  // 408
  k_reduce<<<reduce_blocks, 256, 0, stream>>>(ws, pc13, pc10, pc2, acc,
                                              (unsigned int*)(ws + 55304), out);
}

// Round 10
// 76.548 us; speedup vs baseline: 1.0833x; 1.0468x over previous
//
#include <hip/hip_runtime.h>
#include <hip/hip_fp16.h>

// Sizes (fixed):
// pc1_0: [8,2048,3] -> 16384 pts   d_in[0]
// pc1_1: [8, 512,3] ->  4096 pts   d_in[1]
// pc1_3: [8, 256,1] ->  2048 vals  d_in[2]
// pc2  : [8,2048,3] -> 16384 pts   d_in[3]
// pc3  : [8, 256,3] ->  2048 pts   d_in[4]
//
// ws layout (floats):
//   [0      ,16384) minA0 : pc1_0 -> pc2   (cd, a->b)
//   [16384  ,32768) minB0 : pc2   -> pc1_0 (cd, b->a)
//   [32768  ,36864) minA1 : pc1_1 -> pc2   (seed, a->b)
//   [36864  ,53248) minB1 : pc2   -> pc1_1 (seed, b->a)
//   [53248  ,55296) minC  : pc3[b] -> pc2[b] (confidence, full f32)
//   [55296  ,55304) acc[8]
//   [55304]         ticket

#define N_MINS 55296
#define R 4  // A-points per thread (A-chunk = 1024)

__device__ __forceinline__ float blockReduceSum(float v, float* sbuf) {
#pragma unroll
  for (int off = 32; off > 0; off >>= 1) v += __shfl_down(v, off, 64);
  int lane = threadIdx.x & 63;
  int wid  = threadIdx.x >> 6;
  if (lane == 0) sbuf[wid] = v;
  __syncthreads();
  float r = 0.f;
  if (threadIdx.x == 0) r = sbuf[0] + sbuf[1] + sbuf[2] + sbuf[3];
  return r;
}

// Fused NN-min kernel, fp16-packed inner loop:
//   3 __hfma2 (v_pk_fma_f16) + 1 asm v_pk_min_f16 per A-point per 2 B-points
//   = 2 VALU/pair.
// d2 = ra + (w - 2 a.b); ra (|a|^2) kept f32, folded after the min.
// Confidence job stays f32 (feeds exp).
// LDS: tile4[p] = 16B = {(-2x0,-2x1),(-2y0,-2y1),(-2z0,-2z1),(w0,w1)} half2s.
__global__ __launch_bounds__(256) void k_nn_all(
    const float* __restrict__ pc10, const float* __restrict__ pc11,
    const float* __restrict__ pc2, const float* __restrict__ pc3,
    float* __restrict__ ws) {
  const int tid = threadIdx.x;
  const int blk = blockIdx.x;
  __shared__ float4 tile4[256];

  if (blk >= 2560) {  // confidence job: per-batch NN pc3[b] -> pc2[b], f32
    int j = blk - 2560;
    int b = j >> 3;
    int s = j & 7;
    int bi = b * 2048 + s * 256 + tid;
    {
      float bx = pc2[bi * 3 + 0], by = pc2[bi * 3 + 1], bz = pc2[bi * 3 + 2];
      tile4[tid] = make_float4(-2.f * bx, -2.f * by, -2.f * bz,
                               bx * bx + by * by + bz * bz);
    }
    int i = b * 256 + tid;
    float ax = pc3[i * 3 + 0], ay = pc3[i * 3 + 1], az = pc3[i * 3 + 2];
    float ra = ax * ax + ay * ay + az * az;
    __syncthreads();
    float mn = 3.0e38f;
#pragma unroll 4
    for (int t = 0; t < 256; ++t) {
      float4 q = tile4[t];
      float v = fmaf(q.x, ax, fmaf(q.y, ay, fmaf(q.z, az, q.w)));
      mn = fminf(mn, v);
    }
    atomicMin((unsigned int*)(ws + 53248 + i), __float_as_uint(fmaxf(mn + ra, 0.f)));
    return;
  }

  const float* A;
  const float* B;
  float* outMin;
  int aBase, bBase;
  if (blk < 1024) {           // job1: pc1_0 (16384) -> pc2 (16384)
    A = pc10; B = pc2; outMin = ws + 0;
    aBase = (blk >> 6) * 1024; bBase = (blk & 63) * 256;
  } else if (blk < 2048) {    // job2: pc2 (16384) -> pc1_0 (16384)
    int j = blk - 1024;
    A = pc2; B = pc10; outMin = ws + 16384;
    aBase = (j >> 6) * 1024; bBase = (j & 63) * 256;
  } else if (blk < 2304) {    // job3: pc1_1 (4096) -> pc2 (16384)
    int j = blk - 2048;
    A = pc11; B = pc2; outMin = ws + 32768;
    aBase = (j >> 6) * 1024; bBase = (j & 63) * 256;
  } else {                    // job4: pc2 (16384) -> pc1_1 (4096)
    int j = blk - 2304;
    A = pc2; B = pc11; outMin = ws + 36864;
    aBase = (j >> 4) * 1024; bBase = (j & 15) * 256;
  }

  // stage 256-point B slice as 128 fp16 pair-entries
  if (tid < 128) {
    int bi0 = (bBase + 2 * tid) * 3;
    float x0 = B[bi0 + 0], y0 = B[bi0 + 1], z0 = B[bi0 + 2];
    float x1 = B[bi0 + 3], y1 = B[bi0 + 4], z1 = B[bi0 + 5];
    float4 e;
    e.x = __builtin_bit_cast(float, __floats2half2_rn(-2.f * x0, -2.f * x1));
    e.y = __builtin_bit_cast(float, __floats2half2_rn(-2.f * y0, -2.f * y1));
    e.z = __builtin_bit_cast(float, __floats2half2_rn(-2.f * z0, -2.f * z1));
    e.w = __builtin_bit_cast(float, __floats2half2_rn(x0 * x0 + y0 * y0 + z0 * z0,
                                                      x1 * x1 + y1 * y1 + z1 * z1));
    tile4[tid] = e;
  }

  __half2 axx[R], ayy[R], azz[R];
  float mn2[R];  // bit-patterns of __half2 running minima
  float ra[R];
#pragma unroll
  for (int r = 0; r < R; ++r) {
    int ai = aBase + r * 256 + tid;
    float ax = A[ai * 3 + 0];
    float ay = A[ai * 3 + 1];
    float az = A[ai * 3 + 2];
    axx[r] = __float2half2_rn(ax);
    ayy[r] = __float2half2_rn(ay);
    azz[r] = __float2half2_rn(az);
    ra[r] = fmaf(ax, ax, fmaf(ay, ay, az * az));
    mn2[r] = __builtin_bit_cast(float, 0x7BFF7BFFu);  // (65504, 65504)
  }
  __syncthreads();

#pragma unroll 4
  for (int p = 0; p < 128; ++p) {
    float4 q = tile4[p];
    __half2 qx = __builtin_bit_cast(__half2, q.x);
    __half2 qy = __builtin_bit_cast(__half2, q.y);
    __half2 qz = __builtin_bit_cast(__half2, q.z);
    __half2 qw = __builtin_bit_cast(__half2, q.w);
#pragma unroll
    for (int r = 0; r < R; ++r) {
      __half2 v = __hfma2(qx, axx[r], __hfma2(qy, ayy[r], __hfma2(qz, azz[r], qw)));
      float vb = __builtin_bit_cast(float, v);
      asm("v_pk_min_f16 %0, %0, %1" : "+v"(mn2[r]) : "v"(vb));
    }
  }

#pragma unroll
  for (int r = 0; r < R; ++r) {
    int ai = aBase + r * 256 + tid;
    __half2 m = __builtin_bit_cast(__half2, mn2[r]);
    float mnf = fminf(__low2float(m), __high2float(m));
    atomicMin((unsigned int*)(outMin + ai),
              __float_as_uint(fmaxf(mnf + ra[r], 0.f)));
  }
}

// Segmented reduce + final combine (ticket: last block writes out).
__global__ __launch_bounds__(256) void k_reduce(
    const float* __restrict__ ws, const float* __restrict__ pc13,
    const float* __restrict__ pc10, const float* __restrict__ pc2,
    float* __restrict__ acc, unsigned int* __restrict__ ticket,
    float* __restrict__ out) {
  __shared__ float sbuf[4];
  int idx = blockIdx.x * 256 + threadIdx.x;
  float v;
  int k;
  if (idx < 53248) {
    v = sqrtf(fmaxf(ws[idx], 0.f));
    k = (idx < 16384) ? 0 : (idx < 32768) ? 1 : (idx < 36864) ? 2 : 3;
  } else if (idx < 55296) {
    int i = idx - 53248;
    float score = expf(-sqrtf(fmaxf(ws[idx], 0.f)));
    float d = pc13[i] - score;
    v = d * d;
    k = 4;
  } else {
    int i = idx - 55296;
    float d = pc10[i] - pc2[i];
    v = d * d;
    k = 5;
  }
  float s = blockReduceSum(v, sbuf);
  if (threadIdx.x == 0) {
    atomicAdd(acc + k, s);
    __threadfence();
    unsigned int t = atomicAdd(ticket, 1u);
    if (t == gridDim.x - 1) {
      __threadfence();
      float cd   = (acc[0] + acc[1]) * (1.f / 16384.f);
      float seed = acc[2] * (1.f / 4096.f) + acc[3] * (1.f / 16384.f);
      float conf = acc[4] * (1.f / 2048.f);
      float p2p  = acc[5] * (1.f / 49152.f);
      out[0] = 0.5f * cd + 0.5f * seed + 0.5f * conf + p2p;
    }
  }
}

extern "C" void kernel_launch(void* const* d_in, const int* in_sizes, int n_in,
                              void* d_out, int out_size, void* d_ws, size_t ws_size,
                              hipStream_t stream) {
  const float* pc10 = (const float*)d_in[0];
  const float* pc11 = (const float*)d_in[1];
  const float* pc13 = (const float*)d_in[2];
  const float* pc2  = (const float*)d_in[3];
  const float* pc3  = (const float*)d_in[4];
  float* ws  = (float*)d_ws;
  float* acc = ws + N_MINS;
  float* out = (float*)d_out;

  // init: min arrays to ~3.39e38 (0x7F7F7F7F); acc[8]+ticket to 0
  (void)hipMemsetAsync(ws, 0x7F, N_MINS * sizeof(float), stream);
  (void)hipMemsetAsync(acc, 0, 9 * sizeof(float), stream);

  k_nn_all<<<2624, 256, 0, stream>>>(pc10, pc11, pc2, pc3, ws);

  int reduce_blocks = (N_MINS + 49152) / 256;  // 408
  k_reduce<<<reduce_blocks, 256, 0, stream>>>(ws, pc13, pc10, pc2, acc,
                                              (unsigned int*)(ws + 55304), out);
}